// Round 9
// baseline (141.623 us; speedup 1.0000x reference)
//
#include <hip/hip_runtime.h>
#include <hip/hip_bf16.h>
#include <math.h>

typedef __attribute__((ext_vector_type(8))) short short8;
typedef __attribute__((ext_vector_type(4))) float f32x4;
typedef __attribute__((ext_vector_type(4))) unsigned int u32x4;

#define NB   128   // batch
#define TT   64    // timesteps (T-1)
#define DD   512   // feature dim
#define HH   128   // hidden dim
#define WVD  128   // wordvec dim
#define VV   10000 // vocab
#define VP   10048 // vocab padded to multiple of 64
#define NROW (NB*TT)
#define NTILE (VP/64)    // 157 column tiles of 64
#define VT   32          // col-tile streams (blocks per row-block)
#define TILE_BYTES 16384 // 64 cols x 128 k x 2 B
#define LOG2E 1.44269504088896f
#define LN2   0.69314718055995f

__device__ __forceinline__ unsigned short f2bf(float x) {
  union { float f; unsigned int u; } v; v.f = x;
  unsigned int r = v.u + 0x7fffu + ((v.u >> 16) & 1u);
  return (unsigned short)(r >> 16);
}
__device__ __forceinline__ float bf2f(unsigned short u) {
  union { unsigned int i; float f; } v; v.i = ((unsigned int)u) << 16; return v.f;
}
__device__ __forceinline__ short8 cvt2bf8(f32x4 a, f32x4 b) {
  short8 t;
  t[0]=(short)f2bf(a[0]); t[1]=(short)f2bf(a[1]);
  t[2]=(short)f2bf(a[2]); t[3]=(short)f2bf(a[3]);
  t[4]=(short)f2bf(b[0]); t[5]=(short)f2bf(b[1]);
  t[6]=(short)f2bf(b[2]); t[7]=(short)f2bf(b[3]);
  return t;
}

// ---------------------------------------------------------------------------
// K_main: one fused launch.
//   b in [0,8)     : MFMA recurrence for 16 samples (n = b*16 .. +16):
//                    h0 via MFMA, then 64 steps of
//                    H_{t+1} = tanh(H_t @ Whh^T + X_t), X computed in-loop
//                    by MFMA from embed rows; streams bf16 h to hsb.
//   b in [8,322)   : Wvt[v][k] = bf16(W_vocab[k][v] * LOG2E) (tile transpose)
//   b in [322,362) : expbv[v] = exp(b_vocab[v]) (0 for pad)
//   b == 362       : out = 0
// RNN LDS: H double-buffered [2][16 samples][128 j] bf16, XOR-swizzled rows
// (row=sample s, byte = s*256 + ((j*2) ^ ((s&7)<<4))). 8 KB of the 16.6 KB
// union (transpose tile needs 64*65*4).
// ---------------------------------------------------------------------------
__global__ __launch_bounds__(256) void k_main(
    const float* __restrict__ Wv, unsigned short* __restrict__ Wvt,
    const float* __restrict__ bv, float* __restrict__ expbv,
    float* __restrict__ out,
    const float* __restrict__ features, const float* __restrict__ Wp,
    const float* __restrict__ bp,
    const int* __restrict__ captions, const float* __restrict__ embed,
    const float* __restrict__ Wih, const float* __restrict__ bih,
    const float* __restrict__ bhh, const float* __restrict__ Whh,
    unsigned short* __restrict__ hsb) {
  __shared__ __align__(16) char smem[16640];
  int b = blockIdx.x, tid = threadIdx.x;

  if (b >= 8) {
    if (b < 322) {
      // ---- W_vocab transpose tile (fold LOG2E into wvt) ----
      float (*tile)[65] = (float (*)[65])smem;
      int tb = b - 8;
      int bvv = (tb >> 1) * 64;
      int bk  = (tb & 1) * 64;
      int tv = tid & 63;
      int tk0 = tid >> 6;
      #pragma unroll
      for (int kk = 0; kk < 64; kk += 4) {
        int k = bk + kk + tk0;
        int v = bvv + tv;
        tile[kk + tk0][tv] = (v < VV) ? Wv[(size_t)k*VV + v] : 0.f;
      }
      __syncthreads();
      int tk = tid & 63;
      int tv0 = tid >> 6;
      #pragma unroll
      for (int vv = 0; vv < 64; vv += 4) {
        int v = bvv + vv + tv0;
        Wvt[(size_t)v*HH + bk + tk] = f2bf(tile[tk][vv + tv0] * LOG2E);
      }
    } else if (b < 362) {
      int v = (b - 322)*256 + tid;
      if (v < VP) expbv[v] = (v < VV) ? __expf(bv[v]) : 0.f;
    } else {
      if (tid == 0) out[0] = 0.f;
    }
    return;
  }

  // ===================== MFMA recurrence, samples [b*16, b*16+16) ==========
  int n0 = b * 16;
  int w = tid >> 6, l = tid & 63;
  int l4 = l >> 4, lc = l & 15;

  // persistent B-fragments: wave w owns col-tiles {2w, 2w+1} (j in [w*32,+32))
  short8 bw[2][4];    // Whh rows (bf16)
  short8 bwih[2][4];  // Wih rows (bf16)
  float bihbhh[2];
  int jcol[2];
  #pragma unroll
  for (int c = 0; c < 2; ++c) {
    int jc = (2*w + c)*16 + lc;
    jcol[c] = jc;
    bihbhh[c] = bih[jc] + bhh[jc];
    #pragma unroll
    for (int ks = 0; ks < 4; ++ks) {
      const float* p = Whh + (size_t)jc*HH + ks*32 + l4*8;
      bw[c][ks] = cvt2bf8(*(const f32x4*)p, *(const f32x4*)(p+4));
      const float* q = Wih + (size_t)jc*WVD + ks*32 + l4*8;
      bwih[c][ks] = cvt2bf8(*(const f32x4*)q, *(const f32x4*)(q+4));
    }
  }

  // ---- h0 = features @ W_proj + b_proj  (MFMA, K=512) -> H[0] ----
  {
    f32x4 acc0[2] = {{0.f,0.f,0.f,0.f},{0.f,0.f,0.f,0.f}};
    #pragma unroll
    for (int ks = 0; ks < 16; ++ks) {
      int k0 = ks*32 + l4*8;
      const float* fp = features + (size_t)(n0 + lc)*DD + k0;
      short8 aF = cvt2bf8(*(const f32x4*)fp, *(const f32x4*)(fp+4));
      #pragma unroll
      for (int c = 0; c < 2; ++c) {
        short8 bF;
        #pragma unroll
        for (int i2 = 0; i2 < 8; ++i2)
          bF[i2] = (short)f2bf(Wp[(size_t)(k0+i2)*HH + jcol[c]]);
        acc0[c] = __builtin_amdgcn_mfma_f32_16x16x32_bf16(aF, bF, acc0[c], 0,0,0);
      }
    }
    #pragma unroll
    for (int c = 0; c < 2; ++c) {
      float bpv = bp[jcol[c]];
      #pragma unroll
      for (int jj = 0; jj < 4; ++jj) {
        int s = l4*4 + jj;
        *(unsigned short*)(smem + s*256 + ((jcol[c]*2) ^ ((s&7)<<4))) =
            f2bf(acc0[c][jj] + bpv);
      }
    }
  }

  // ---- xb for t=0 (MFMA from embed rows) ----
  f32x4 xcur[2] = {{0.f,0.f,0.f,0.f},{0.f,0.f,0.f,0.f}};
  {
    int tok = captions[(n0 + lc)*65 + 0];
    #pragma unroll
    for (int ks = 0; ks < 4; ++ks) {
      const float* ep = embed + (size_t)tok*WVD + ks*32 + l4*8;
      short8 aX = cvt2bf8(*(const f32x4*)ep, *(const f32x4*)(ep+4));
      xcur[0] = __builtin_amdgcn_mfma_f32_16x16x32_bf16(aX, bwih[0][ks], xcur[0], 0,0,0);
      xcur[1] = __builtin_amdgcn_mfma_f32_16x16x32_bf16(aX, bwih[1][ks], xcur[1], 0,0,0);
    }
  }
  __syncthreads();   // H[0] visible to all waves

  // flush lane mapping (per-step hsb stream)
  int fs = tid >> 4;                 // sample 0..15
  int fo = (tid & 15) * 16;          // linear byte offset in row
  int frd = fo ^ ((fs & 7) << 4);    // swizzled read offset

  int cur = 0;
  for (int t = 0; t < TT; ++t) {
    // A-fragments of h_t from H[cur] (swizzled, conflict-free)
    short8 ah[4];
    #pragma unroll
    for (int ks = 0; ks < 4; ++ks)
      ah[ks] = *(const short8*)(smem + cur*4096 + lc*256 +
                                ((ks*64 + l4*16) ^ ((lc&7)<<4)));
    // issue embed gather for t+1 early (hidden under MFMA below)
    f32x4 xnext[2] = {{0.f,0.f,0.f,0.f},{0.f,0.f,0.f,0.f}};
    if (t < TT-1) {
      int tok2 = captions[(n0 + lc)*65 + t + 1];
      short8 aX[4];
      #pragma unroll
      for (int ks = 0; ks < 4; ++ks) {
        const float* ep = embed + (size_t)tok2*WVD + ks*32 + l4*8;
        aX[ks] = cvt2bf8(*(const f32x4*)ep, *(const f32x4*)(ep+4));
      }
      #pragma unroll
      for (int ks = 0; ks < 4; ++ks) {
        xnext[0] = __builtin_amdgcn_mfma_f32_16x16x32_bf16(aX[ks], bwih[0][ks], xnext[0], 0,0,0);
        xnext[1] = __builtin_amdgcn_mfma_f32_16x16x32_bf16(aX[ks], bwih[1][ks], xnext[1], 0,0,0);
      }
    }
    // recurrence MFMA: acc = h_t @ Whh^T
    f32x4 acc[2] = {{0.f,0.f,0.f,0.f},{0.f,0.f,0.f,0.f}};
    #pragma unroll
    for (int ks = 0; ks < 4; ++ks) {
      acc[0] = __builtin_amdgcn_mfma_f32_16x16x32_bf16(ah[ks], bw[0][ks], acc[0], 0,0,0);
      acc[1] = __builtin_amdgcn_mfma_f32_16x16x32_bf16(ah[ks], bw[1][ks], acc[1], 0,0,0);
    }
    // epilogue: h_{t+1} = tanh(acc + xb_t) -> H[cur^1] (bf16, swizzled)
    #pragma unroll
    for (int c = 0; c < 2; ++c) {
      #pragma unroll
      for (int jj = 0; jj < 4; ++jj) {
        int s = l4*4 + jj;
        float v = acc[c][jj] + xcur[c][jj] + bihbhh[c];
        float e = __builtin_amdgcn_exp2f(v * (2.0f*LOG2E));
        float h = 1.0f - 2.0f*__builtin_amdgcn_rcpf(e + 1.0f);  // tanh
        *(unsigned short*)(smem + (cur^1)*4096 + s*256 +
                           ((jcol[c]*2) ^ ((s&7)<<4))) = f2bf(h);
      }
    }
    __syncthreads();
    // stream h_{t+1} -> hsb[n][t][:] (coalesced 16B/lane)
    u32x4 fr = *(const u32x4*)(smem + (cur^1)*4096 + fs*256 + frd);
    *(u32x4*)(hsb + ((size_t)(n0 + fs)*TT + t)*HH + (fo >> 1)) = fr;
    xcur[0] = xnext[0]; xcur[1] = xnext[1];
    cur ^= 1;
  }
}

// ---------------------------------------------------------------------------
// K_loss: sum-exp of scores via LDS-staged B, 2-phase pipeline.
// (hsb now holds unscaled bf16 h; wvt carries the LOG2E factor.)
// ---------------------------------------------------------------------------
__global__ __launch_bounds__(256) void k_loss(
    const unsigned short* __restrict__ hsb,
    const unsigned short* __restrict__ wvt,
    const float* __restrict__ expbv,
    float* __restrict__ se_part) {
  __shared__ unsigned short bt[2][TILE_BYTES/2];   // 2 x 16 KB
  int tid = threadIdx.x;
  int w = tid >> 6, l = tid & 63;
  int l4 = l >> 4, lc = l & 15;
  int rb = blockIdx.x >> 5;
  int vt = blockIdx.x & 31;
  int wrow = rb*256 + w*64;

  short8 af[4][4];
  #pragma unroll
  for (int sm = 0; sm < 4; ++sm)
    #pragma unroll
    for (int ks = 0; ks < 4; ++ks)
      af[sm][ks] = *(const short8*)(hsb + (size_t)(wrow + sm*16 + lc)*HH + ks*32 + l4*8);

  int T = (lc & 7) << 4;
  int sb[4];
  #pragma unroll
  for (int ks = 0; ks < 4; ++ks) sb[ks] = ((ks*64) + l4*16) ^ T;

#define STAGE(bufi, ct) do {                                                  \
    const char* _gb = (const char*)wvt + (size_t)(ct)*TILE_BYTES;             \
    _Pragma("unroll")                                                         \
    for (int q = 0; q < 4; ++q) {                                             \
      int _off = w*4096 + q*1024 + l*16;                                      \
      int _src = _off ^ (((_off >> 8) & 7) << 4);                             \
      __builtin_amdgcn_global_load_lds(                                       \
        (const __attribute__((address_space(1))) void*)(_gb + _src),          \
        (__attribute__((address_space(3))) void*)((char*)&bt[bufi][0] + w*4096 + q*1024), \
        16, 0, 0);                                                            \
    }                                                                         \
  } while (0)

#define EBLOAD(dst, ct) do {                                                  \
    const float* _e = expbv + (ct)*64 + lc;                                   \
    dst[0] = _e[0]; dst[1] = _e[16]; dst[2] = _e[32]; dst[3] = _e[48];        \
  } while (0)

#define COMPUTE(bufi, ebv_) do {                                              \
    const char* _Bb = (const char*)&bt[bufi][0];                              \
    _Pragma("unroll")                                                         \
    for (int st = 0; st < 4; ++st) {                                          \
      const char* _Bs = _Bb + st*4096 + lc*256;                               \
      short8 _b0 = *(const short8*)(_Bs + sb[0]);                             \
      short8 _b1 = *(const short8*)(_Bs + sb[1]);                             \
      short8 _b2 = *(const short8*)(_Bs + sb[2]);                             \
      short8 _b3 = *(const short8*)(_Bs + sb[3]);                             \
      float _eb = ebv_[st];                                                   \
      _Pragma("unroll")                                                       \
      for (int sm = 0; sm < 4; ++sm) {                                        \
        f32x4 _acc = {0.f,0.f,0.f,0.f};                                       \
        _acc = __builtin_amdgcn_mfma_f32_16x16x32_bf16(af[sm][0], _b0, _acc, 0,0,0); \
        _acc = __builtin_amdgcn_mfma_f32_16x16x32_bf16(af[sm][1], _b1, _acc, 0,0,0); \
        _acc = __builtin_amdgcn_mfma_f32_16x16x32_bf16(af[sm][2], _b2, _acc, 0,0,0); \
        _acc = __builtin_amdgcn_mfma_f32_16x16x32_bf16(af[sm][3], _b3, _acc, 0,0,0); \
        _Pragma("unroll")                                                     \
        for (int jj = 0; jj < 4; ++jj)                                        \
          se[sm][jj] = fmaf(__builtin_amdgcn_exp2f(_acc[jj]), _eb, se[sm][jj]); \
      }                                                                       \
    }                                                                         \
  } while (0)

  float se[4][4] = {{0.f}};
  float ebc[4], ebn[4];
  STAGE(0, vt);
  EBLOAD(ebc, vt);
  __syncthreads();
  int i = 0;
  for (;;) {
    int nextct = vt + (i+1)*VT;
    if (nextct < NTILE) { STAGE((i+1)&1, nextct); EBLOAD(ebn, nextct); }
    COMPUTE(i&1, ebc);
    if (nextct >= NTILE) break;
    __syncthreads();
    ebc[0]=ebn[0]; ebc[1]=ebn[1]; ebc[2]=ebn[2]; ebc[3]=ebn[3];
    ++i;
  }

  #pragma unroll
  for (int sm = 0; sm < 4; ++sm)
    #pragma unroll
    for (int jj = 0; jj < 4; ++jj) {
      float v = se[sm][jj];
      v += __shfl_xor(v, 1); v += __shfl_xor(v, 2);
      v += __shfl_xor(v, 4); v += __shfl_xor(v, 8);
      se[sm][jj] = v;
    }
  if (lc == 0) {
    #pragma unroll
    for (int sm = 0; sm < 4; ++sm)
      #pragma unroll
      for (int jj = 0; jj < 4; ++jj)
        se_part[(size_t)vt*NROW + wrow + sm*16 + l4*4 + jj] = se[sm][jj];
  }
#undef STAGE
#undef EBLOAD
#undef COMPUTE
}

// ---------------------------------------------------------------------------
// K_final: sum 32 partials per row + target score + masked NLL reduction.
// part = h . (Wv*log2e) -> score = part*LN2 + bv  (unchanged semantics).
// ---------------------------------------------------------------------------
__global__ __launch_bounds__(256) void k_final(
    const unsigned short* __restrict__ hsb,
    const unsigned short* __restrict__ wvt,
    const float* __restrict__ bv,
    const float* __restrict__ se_part,
    const int* __restrict__ captions,
    float* __restrict__ out) {
  int tid = threadIdx.x;
  int w = tid >> 6, l = tid & 63;
  int row = blockIdx.x*32 + w*8 + (l >> 3);
  int seg = l & 7;
  int n = row >> 6, t = row & 63;
  int tg = captions[n*65 + t + 1];
  float sep = 0.f;
  #pragma unroll
  for (int i = 0; i < 4; ++i)
    sep += se_part[(size_t)(seg*4 + i)*NROW + row];
  float part = 0.f;
  if (tg != 0) {
    const unsigned short* a = hsb + (size_t)row*HH + seg*16;
    const unsigned short* bq = wvt + (size_t)tg*HH + seg*16;
    short8 a0 = *(const short8*)a, a1 = *(const short8*)(a+8);
    short8 b0 = *(const short8*)bq, b1 = *(const short8*)(bq+8);
    #pragma unroll
    for (int i = 0; i < 8; ++i) {
      part += bf2f((unsigned short)a0[i]) * bf2f((unsigned short)b0[i]);
      part += bf2f((unsigned short)a1[i]) * bf2f((unsigned short)b1[i]);
    }
  }
  part += __shfl_xor(part, 1); sep += __shfl_xor(sep, 1);
  part += __shfl_xor(part, 2); sep += __shfl_xor(sep, 2);
  part += __shfl_xor(part, 4); sep += __shfl_xor(sep, 4);
  if (seg == 0 && tg != 0) {
    float score = part * LN2 + bv[tg];
    float nll = logf(sep) - score;
    atomicAdd(out, nll * (1.0f/128.0f));
  }
}

extern "C" void kernel_launch(void* const* d_in, const int* in_sizes, int n_in,
                              void* d_out, int out_size, void* d_ws, size_t ws_size,
                              hipStream_t stream) {
  const float* features = (const float*)d_in[0];
  const int*   captions = (const int*)d_in[1];
  const float* W_proj   = (const float*)d_in[2];
  const float* b_proj   = (const float*)d_in[3];
  const float* embed    = (const float*)d_in[4];
  const float* W_ih     = (const float*)d_in[5];
  const float* W_hh     = (const float*)d_in[6];
  const float* b_ih     = (const float*)d_in[7];
  const float* b_hh     = (const float*)d_in[8];
  const float* W_vocab  = (const float*)d_in[9];
  const float* b_vocab  = (const float*)d_in[10];
  float* out = (float*)d_out;
  char* ws = (char*)d_ws;

  float*          se_part = (float*)(ws + 0x010000);            // 1 MB
  unsigned short* hsb     = (unsigned short*)(ws + 0x410000);   // 2 MB
  unsigned short* wvt     = (unsigned short*)(ws + 0x620000);   // 2.57 MB
  float*          expbv   = (float*)(ws + 0x8A0000);            // 40 KB

  hipLaunchKernelGGL(k_main, dim3(363), dim3(256), 0, stream,
                     W_vocab, wvt, b_vocab, expbv, out,
                     features, W_proj, b_proj, captions, embed,
                     W_ih, b_ih, b_hh, W_hh, hsb);
  hipLaunchKernelGGL(k_loss, dim3(32*VT), dim3(256), 0, stream,
                     hsb, wvt, expbv, se_part);
  hipLaunchKernelGGL(k_final, dim3(NROW/32), dim3(256), 0, stream,
                     hsb, wvt, b_vocab, se_part, captions, out);
}

// Round 10
// 108.214 us; speedup vs baseline: 1.3087x; 1.3087x over previous
//
#include <hip/hip_runtime.h>
#include <hip/hip_bf16.h>
#include <math.h>

typedef __attribute__((ext_vector_type(8))) short short8;
typedef __attribute__((ext_vector_type(4))) float f32x4;
typedef __attribute__((ext_vector_type(4))) unsigned int u32x4;

#define NB   128   // batch
#define TT   64    // timesteps (T-1)
#define DD   512   // feature dim
#define HH   128   // hidden dim
#define WVD  128   // wordvec dim
#define VV   10000 // vocab
#define VP   10048 // vocab padded to multiple of 64
#define NROW (NB*TT)
#define NTILE (VP/64)    // 157 column tiles of 64
#define VT   32          // col-tile streams (blocks per row-block)
#define TILE_BYTES 16384 // 64 cols x 128 k x 2 B
#define LOG2E 1.44269504088896f
#define LN2   0.69314718055995f

__device__ __forceinline__ unsigned short f2bf(float x) {
  union { float f; unsigned int u; } v; v.f = x;
  unsigned int r = v.u + 0x7fffu + ((v.u >> 16) & 1u);
  return (unsigned short)(r >> 16);
}
__device__ __forceinline__ float bf2f(unsigned short u) {
  union { unsigned int i; float f; } v; v.i = ((unsigned int)u) << 16; return v.f;
}
__device__ __forceinline__ short8 cvt2bf8(f32x4 a, f32x4 b) {
  short8 t;
  t[0]=(short)f2bf(a[0]); t[1]=(short)f2bf(a[1]);
  t[2]=(short)f2bf(a[2]); t[3]=(short)f2bf(a[3]);
  t[4]=(short)f2bf(b[0]); t[5]=(short)f2bf(b[1]);
  t[6]=(short)f2bf(b[2]); t[7]=(short)f2bf(b[3]);
  return t;
}

// ---------------------------------------------------------------------------
// K_pre: everything the recurrence loop must NOT touch.
//   [0,314)    : Wvt[v][k] = bf16(W_vocab[k][v] * LOG2E) (64x64 tile transpose)
//   [314,354)  : expbv[v] = exp(b_vocab[v]) (0 for pad)
//   354        : out = 0
//   [355,483)  : h0[n] = features[n] @ W_proj + b_proj (VALU GEMV, n = b-355)
//   [483,515)  : xbt = gather(embed) @ W_ih^T + b_ih + b_hh  (MFMA, 256 rows/blk)
// ---------------------------------------------------------------------------
__global__ __launch_bounds__(256) void k_pre(
    const float* __restrict__ Wv, unsigned short* __restrict__ Wvt,
    const float* __restrict__ bv, float* __restrict__ expbv,
    float* __restrict__ out,
    const float* __restrict__ features, const float* __restrict__ Wp,
    const float* __restrict__ bp, float* __restrict__ h0,
    const int* __restrict__ captions, const float* __restrict__ embed,
    const float* __restrict__ Wih, const float* __restrict__ bih,
    const float* __restrict__ bhh, float* __restrict__ xbt) {
  __shared__ __align__(16) char smem[32768];
  int b = blockIdx.x, tid = threadIdx.x;

  if (b < 314) {
    // ---- W_vocab transpose tile (fold LOG2E) ----
    float (*tile)[65] = (float (*)[65])smem;
    int bvv = (b >> 1) * 64;
    int bk  = (b & 1) * 64;
    int tv = tid & 63;
    int tk0 = tid >> 6;
    #pragma unroll
    for (int kk = 0; kk < 64; kk += 4) {
      int k = bk + kk + tk0;
      int v = bvv + tv;
      tile[kk + tk0][tv] = (v < VV) ? Wv[(size_t)k*VV + v] : 0.f;
    }
    __syncthreads();
    int tk = tid & 63;
    int tv0 = tid >> 6;
    #pragma unroll
    for (int vv = 0; vv < 64; vv += 4) {
      int v = bvv + vv + tv0;
      Wvt[(size_t)v*HH + bk + tk] = f2bf(tile[tk][vv + tv0] * LOG2E);
    }
  } else if (b < 354) {
    int v = (b - 314)*256 + tid;
    if (v < VP) expbv[v] = (v < VV) ? __expf(bv[v]) : 0.f;
  } else if (b == 354) {
    if (tid == 0) out[0] = 0.f;
  } else if (b < 483) {
    // ---- h0 for sample n (VALU GEMV, coalesced over j) ----
    int n = b - 355;
    float* fl  = (float*)smem;                  // 512 f
    f32x4* red = (f32x4*)(smem + 2048);         // 256 f32x4
    fl[tid]       = features[n*DD + tid];
    fl[tid + 256] = features[n*DD + 256 + tid];
    __syncthreads();
    int jq = (tid & 31) * 4;
    int ks = tid >> 5;
    f32x4 acc = {0.f,0.f,0.f,0.f};
    const float* wp = Wp + (size_t)(ks*64)*HH + jq;
    #pragma unroll 4
    for (int k = 0; k < 64; ++k) {
      f32x4 wv = *(const f32x4*)(wp + (size_t)k*HH);
      acc += fl[ks*64 + k] * wv;
    }
    red[ks*32 + (tid & 31)] = acc;
    __syncthreads();
    if (tid < 32) {
      f32x4 s = red[tid];
      #pragma unroll
      for (int i = 1; i < 8; ++i) s += red[i*32 + tid];
      s += *(const f32x4*)(bp + tid*4);
      *(f32x4*)(h0 + n*HH + tid*4) = s;
    }
  } else {
    // ---- xbt GEMM: rows [(b-483)*256, +256), all 128 cols ----
    char* wihbf = smem;   // 32 KB swizzled bf16 Wih
    int w = tid >> 6, l = tid & 63;
    int l4 = l >> 4, lc = l & 15;
    {
      int row = tid >> 1, half = tid & 1;
      const float* src = Wih + (size_t)row*WVD + half*64;
      #pragma unroll
      for (int i = 0; i < 8; ++i) {
        f32x4 a = *(const f32x4*)(src + i*8);
        f32x4 c = *(const f32x4*)(src + i*8 + 4);
        int chunk = half*8 + i;
        *(short8*)(wihbf + row*256 + ((chunk << 4) ^ ((row & 7) << 4))) = cvt2bf8(a, c);
      }
    }
    int wrow = (b - 483)*256 + w*64;
    // A fragments: gather embed rows per caption token
    short8 af[4][4];
    #pragma unroll
    for (int sm = 0; sm < 4; ++sm) {
      int r = wrow + sm*16 + lc;
      int n = r >> 6, t = r & 63;
      const float* x = embed + (size_t)captions[n*65 + t] * WVD;
      #pragma unroll
      for (int ks = 0; ks < 4; ++ks) {
        const float* p = x + ks*32 + l4*8;
        af[sm][ks] = cvt2bf8(*(const f32x4*)p, *(const f32x4*)(p+4));
      }
    }
    __syncthreads();
    #pragma unroll
    for (int ct = 0; ct < 8; ++ct) {
      int rowb = ct*16 + lc;
      short8 bf[4];
      #pragma unroll
      for (int ks = 0; ks < 4; ++ks)
        bf[ks] = *(const short8*)(wihbf + rowb*256 + (((ks*4 + l4) << 4) ^ ((rowb & 7) << 4)));
      int col = ct*16 + lc;
      float bb = bih[col] + bhh[col];
      #pragma unroll
      for (int sm = 0; sm < 4; ++sm) {
        f32x4 acc = {0.f,0.f,0.f,0.f};
        #pragma unroll
        for (int ks = 0; ks < 4; ++ks)
          acc = __builtin_amdgcn_mfma_f32_16x16x32_bf16(af[sm][ks], bf[ks], acc, 0, 0, 0);
        #pragma unroll
        for (int jj = 0; jj < 4; ++jj)
          xbt[(size_t)(wrow + sm*16 + l4*4 + jj)*HH + col] = acc[jj] + bb;
      }
    }
  }
}

// ---------------------------------------------------------------------------
// K_rnn: MFMA recurrence, 8 blocks x 16 samples. Loop touches LDS + regs only;
// xbt rows register-prefetched 3 steps ahead (coalesced 64B dword loads).
// H double-buffered [2][16][128] bf16, XOR-swizzled rows (byte =
// s*256 + ((j*2) ^ ((s&7)<<4))). One barrier/step.
// ---------------------------------------------------------------------------
__global__ __launch_bounds__(256) void k_rnn(
    const float* __restrict__ h0, const float* __restrict__ xbt,
    const float* __restrict__ Whh, unsigned short* __restrict__ hsb) {
  __shared__ __align__(16) char smem[8192];
  int b = blockIdx.x, tid = threadIdx.x;
  int n0 = b * 16;
  int w = tid >> 6, l = tid & 63;
  int l4 = l >> 4, lc = l & 15;

  // persistent Whh B-fragments: wave w owns col-tiles {2w, 2w+1}
  short8 bw[2][4];
  int jcol[2];
  #pragma unroll
  for (int c = 0; c < 2; ++c) {
    int jc = (2*w + c)*16 + lc;
    jcol[c] = jc;
    #pragma unroll
    for (int ks = 0; ks < 4; ++ks) {
      const float* p = Whh + (size_t)jc*HH + ks*32 + l4*8;
      bw[c][ks] = cvt2bf8(*(const f32x4*)p, *(const f32x4*)(p+4));
    }
  }

  // H[0] <- h0 (bf16, swizzled)
  {
    int s = tid >> 4, ch = tid & 15;
    const float* p = h0 + (size_t)(n0 + s)*HH + ch*8;
    f32x4 a = *(const f32x4*)p;
    f32x4 c = *(const f32x4*)(p + 4);
    *(short8*)(smem + s*256 + ((ch*16) ^ ((s&7)<<4))) = cvt2bf8(a, c);
  }

#define XLOAD(dst, t_) do {                                                   \
    if ((t_) < TT) {                                                          \
      _Pragma("unroll")                                                       \
      for (int c = 0; c < 2; ++c) {                                           \
        _Pragma("unroll")                                                     \
        for (int jj = 0; jj < 4; ++jj) {                                      \
          int s_ = l4*4 + jj;                                                 \
          dst[c][jj] = xbt[((size_t)(n0 + s_)*TT + (t_))*HH + jcol[c]];       \
        }                                                                     \
      }                                                                       \
    }                                                                         \
  } while (0)

  f32x4 x0[2], x1[2], x2[2];
  XLOAD(x0, 0); XLOAD(x1, 1); XLOAD(x2, 2);
  __syncthreads();   // H[0] visible

  // hsb stream lane mapping
  int fs = tid >> 4;
  int fo = (tid & 15) * 16;
  int frd = fo ^ ((fs & 7) << 4);

  int cur = 0;
  for (int t = 0; t < TT; ++t) {
    // A-fragments of h_t (swizzled, conflict-free)
    short8 ah[4];
    #pragma unroll
    for (int ks = 0; ks < 4; ++ks)
      ah[ks] = *(const short8*)(smem + cur*4096 + lc*256 +
                                ((ks*64 + l4*16) ^ ((lc&7)<<4)));
    // recurrence MFMA: acc = h_t @ Whh^T
    f32x4 acc[2] = {{0.f,0.f,0.f,0.f},{0.f,0.f,0.f,0.f}};
    #pragma unroll
    for (int ks = 0; ks < 4; ++ks) {
      acc[0] = __builtin_amdgcn_mfma_f32_16x16x32_bf16(ah[ks], bw[0][ks], acc[0], 0,0,0);
      acc[1] = __builtin_amdgcn_mfma_f32_16x16x32_bf16(ah[ks], bw[1][ks], acc[1], 0,0,0);
    }
    // epilogue: h_{t+1} = tanh(acc + xb_t) -> H[cur^1]
    #pragma unroll
    for (int c = 0; c < 2; ++c) {
      #pragma unroll
      for (int jj = 0; jj < 4; ++jj) {
        int s = l4*4 + jj;
        float v = acc[c][jj] + x0[c][jj];
        float e = __builtin_amdgcn_exp2f(v * (2.0f*LOG2E));
        float h = 1.0f - 2.0f*__builtin_amdgcn_rcpf(e + 1.0f);  // tanh
        *(unsigned short*)(smem + (cur^1)*4096 + s*256 +
                           ((jcol[c]*2) ^ ((s&7)<<4))) = f2bf(h);
      }
    }
    // rotate prefetch regs, issue load for t+3 (completes ~3 steps later)
    x0[0]=x1[0]; x0[1]=x1[1];
    x1[0]=x2[0]; x1[1]=x2[1];
    XLOAD(x2, t+3);
    __syncthreads();
    // stream h_{t+1} -> hsb (coalesced 16B/lane)
    u32x4 fr = *(const u32x4*)(smem + (cur^1)*4096 + fs*256 + frd);
    *(u32x4*)(hsb + ((size_t)(n0 + fs)*TT + t)*HH + (fo >> 1)) = fr;
    cur ^= 1;
  }
#undef XLOAD
}

// ---------------------------------------------------------------------------
// K_loss: sum-exp of scores via LDS-staged B, 2-phase pipeline.
// (hsb holds unscaled bf16 h; wvt carries the LOG2E factor.)
// ---------------------------------------------------------------------------
__global__ __launch_bounds__(256) void k_loss(
    const unsigned short* __restrict__ hsb,
    const unsigned short* __restrict__ wvt,
    const float* __restrict__ expbv,
    float* __restrict__ se_part) {
  __shared__ unsigned short bt[2][TILE_BYTES/2];   // 2 x 16 KB
  int tid = threadIdx.x;
  int w = tid >> 6, l = tid & 63;
  int l4 = l >> 4, lc = l & 15;
  int rb = blockIdx.x >> 5;
  int vt = blockIdx.x & 31;
  int wrow = rb*256 + w*64;

  short8 af[4][4];
  #pragma unroll
  for (int sm = 0; sm < 4; ++sm)
    #pragma unroll
    for (int ks = 0; ks < 4; ++ks)
      af[sm][ks] = *(const short8*)(hsb + (size_t)(wrow + sm*16 + lc)*HH + ks*32 + l4*8);

  int T = (lc & 7) << 4;
  int sb[4];
  #pragma unroll
  for (int ks = 0; ks < 4; ++ks) sb[ks] = ((ks*64) + l4*16) ^ T;

#define STAGE(bufi, ct) do {                                                  \
    const char* _gb = (const char*)wvt + (size_t)(ct)*TILE_BYTES;             \
    _Pragma("unroll")                                                         \
    for (int q = 0; q < 4; ++q) {                                             \
      int _off = w*4096 + q*1024 + l*16;                                      \
      int _src = _off ^ (((_off >> 8) & 7) << 4);                             \
      __builtin_amdgcn_global_load_lds(                                       \
        (const __attribute__((address_space(1))) void*)(_gb + _src),          \
        (__attribute__((address_space(3))) void*)((char*)&bt[bufi][0] + w*4096 + q*1024), \
        16, 0, 0);                                                            \
    }                                                                         \
  } while (0)

#define EBLOAD(dst, ct) do {                                                  \
    const float* _e = expbv + (ct)*64 + lc;                                   \
    dst[0] = _e[0]; dst[1] = _e[16]; dst[2] = _e[32]; dst[3] = _e[48];        \
  } while (0)

#define COMPUTE(bufi, ebv_) do {                                              \
    const char* _Bb = (const char*)&bt[bufi][0];                              \
    _Pragma("unroll")                                                         \
    for (int st = 0; st < 4; ++st) {                                          \
      const char* _Bs = _Bb + st*4096 + lc*256;                               \
      short8 _b0 = *(const short8*)(_Bs + sb[0]);                             \
      short8 _b1 = *(const short8*)(_Bs + sb[1]);                             \
      short8 _b2 = *(const short8*)(_Bs + sb[2]);                             \
      short8 _b3 = *(const short8*)(_Bs + sb[3]);                             \
      float _eb = ebv_[st];                                                   \
      _Pragma("unroll")                                                       \
      for (int sm = 0; sm < 4; ++sm) {                                        \
        f32x4 _acc = {0.f,0.f,0.f,0.f};                                       \
        _acc = __builtin_amdgcn_mfma_f32_16x16x32_bf16(af[sm][0], _b0, _acc, 0,0,0); \
        _acc = __builtin_amdgcn_mfma_f32_16x16x32_bf16(af[sm][1], _b1, _acc, 0,0,0); \
        _acc = __builtin_amdgcn_mfma_f32_16x16x32_bf16(af[sm][2], _b2, _acc, 0,0,0); \
        _acc = __builtin_amdgcn_mfma_f32_16x16x32_bf16(af[sm][3], _b3, _acc, 0,0,0); \
        _Pragma("unroll")                                                     \
        for (int jj = 0; jj < 4; ++jj)                                        \
          se[sm][jj] = fmaf(__builtin_amdgcn_exp2f(_acc[jj]), _eb, se[sm][jj]); \
      }                                                                       \
    }                                                                         \
  } while (0)

  float se[4][4] = {{0.f}};
  float ebc[4], ebn[4];
  STAGE(0, vt);
  EBLOAD(ebc, vt);
  __syncthreads();
  int i = 0;
  for (;;) {
    int nextct = vt + (i+1)*VT;
    if (nextct < NTILE) { STAGE((i+1)&1, nextct); EBLOAD(ebn, nextct); }
    COMPUTE(i&1, ebc);
    if (nextct >= NTILE) break;
    __syncthreads();
    ebc[0]=ebn[0]; ebc[1]=ebn[1]; ebc[2]=ebn[2]; ebc[3]=ebn[3];
    ++i;
  }

  #pragma unroll
  for (int sm = 0; sm < 4; ++sm)
    #pragma unroll
    for (int jj = 0; jj < 4; ++jj) {
      float v = se[sm][jj];
      v += __shfl_xor(v, 1); v += __shfl_xor(v, 2);
      v += __shfl_xor(v, 4); v += __shfl_xor(v, 8);
      se[sm][jj] = v;
    }
  if (lc == 0) {
    #pragma unroll
    for (int sm = 0; sm < 4; ++sm)
      #pragma unroll
      for (int jj = 0; jj < 4; ++jj)
        se_part[(size_t)vt*NROW + wrow + sm*16 + l4*4 + jj] = se[sm][jj];
  }
#undef STAGE
#undef EBLOAD
#undef COMPUTE
}

// ---------------------------------------------------------------------------
// K_final: sum 32 partials per row + target score + masked NLL reduction.
// ---------------------------------------------------------------------------
__global__ __launch_bounds__(256) void k_final(
    const unsigned short* __restrict__ hsb,
    const unsigned short* __restrict__ wvt,
    const float* __restrict__ bv,
    const float* __restrict__ se_part,
    const int* __restrict__ captions,
    float* __restrict__ out) {
  int tid = threadIdx.x;
  int w = tid >> 6, l = tid & 63;
  int row = blockIdx.x*32 + w*8 + (l >> 3);
  int seg = l & 7;
  int n = row >> 6, t = row & 63;
  int tg = captions[n*65 + t + 1];
  float sep = 0.f;
  #pragma unroll
  for (int i = 0; i < 4; ++i)
    sep += se_part[(size_t)(seg*4 + i)*NROW + row];
  float part = 0.f;
  if (tg != 0) {
    const unsigned short* a = hsb + (size_t)row*HH + seg*16;
    const unsigned short* bq = wvt + (size_t)tg*HH + seg*16;
    short8 a0 = *(const short8*)a, a1 = *(const short8*)(a+8);
    short8 b0 = *(const short8*)bq, b1 = *(const short8*)(bq+8);
    #pragma unroll
    for (int i = 0; i < 8; ++i) {
      part += bf2f((unsigned short)a0[i]) * bf2f((unsigned short)b0[i]);
      part += bf2f((unsigned short)a1[i]) * bf2f((unsigned short)b1[i]);
    }
  }
  part += __shfl_xor(part, 1); sep += __shfl_xor(sep, 1);
  part += __shfl_xor(part, 2); sep += __shfl_xor(sep, 2);
  part += __shfl_xor(part, 4); sep += __shfl_xor(sep, 4);
  if (seg == 0 && tg != 0) {
    float score = part * LN2 + bv[tg];
    float nll = logf(sep) - score;
    atomicAdd(out, nll * (1.0f/128.0f));
  }
}

extern "C" void kernel_launch(void* const* d_in, const int* in_sizes, int n_in,
                              void* d_out, int out_size, void* d_ws, size_t ws_size,
                              hipStream_t stream) {
  const float* features = (const float*)d_in[0];
  const int*   captions = (const int*)d_in[1];
  const float* W_proj   = (const float*)d_in[2];
  const float* b_proj   = (const float*)d_in[3];
  const float* embed    = (const float*)d_in[4];
  const float* W_ih     = (const float*)d_in[5];
  const float* W_hh     = (const float*)d_in[6];
  const float* b_ih     = (const float*)d_in[7];
  const float* b_hh     = (const float*)d_in[8];
  const float* W_vocab  = (const float*)d_in[9];
  const float* b_vocab  = (const float*)d_in[10];
  float* out = (float*)d_out;
  char* ws = (char*)d_ws;

  float*          h0      = (float*)(ws + 0x000000);            // 64 KB
  float*          se_part = (float*)(ws + 0x010000);            // 1 MB
  unsigned short* hsb     = (unsigned short*)(ws + 0x410000);   // 2 MB
  unsigned short* wvt     = (unsigned short*)(ws + 0x620000);   // 2.57 MB
  float*          expbv   = (float*)(ws + 0x8A0000);            // 40 KB
  float*          xbt     = (float*)(ws + 0x8B0000);            // 4 MB

  hipLaunchKernelGGL(k_pre, dim3(515), dim3(256), 0, stream,
                     W_vocab, wvt, b_vocab, expbv, out,
                     features, W_proj, b_proj, h0,
                     captions, embed, W_ih, b_ih, b_hh, xbt);
  hipLaunchKernelGGL(k_rnn, dim3(8), dim3(256), 0, stream,
                     h0, xbt, W_hh, hsb);
  hipLaunchKernelGGL(k_loss, dim3(32*VT), dim3(256), 0, stream,
                     hsb, wvt, expbv, se_part);
  hipLaunchKernelGGL(k_final, dim3(NROW/32), dim3(256), 0, stream,
                     hsb, wvt, b_vocab, se_part, captions, out);
}